// Round 1
// baseline (117.463 us; speedup 1.0000x reference)
//
#include <hip/hip_runtime.h>
#include <math.h>

// SSIM on MI355X, round 7: 8-rows-per-wave, fully barrier-free 1-wave blocks.
// Each 64-lane wave owns a 58x8 output strip: loads a 64x14 haloed window
// (coalesced, 28 dword loads), vertical 7-tap x5 channels in registers,
// writes its private LDS region (row stride 68 words -> bank-uniform reads),
// wave-synchronous read-back for the horizontal 7-tap + SSIM, wave shuffle
// reduce, one global store. No __syncthreads anywhere in the hot kernel.
// vs round 6: vertical halo redundancy 2.5x -> 1.75x (10 rows/4 out ->
// 14 rows/8 out), VMEM instrs per output 5.5 -> 3.0, no block barrier.

#define WI 320
#define HI 320
#define NI 64
#define TWO 58                  // output cols per x-tile (64 loaded incl. halo)
#define GXD 6                   // ceil(320/58)
#define RPW 8                   // output rows per wave (= per block)
#define GYD (HI / RPW)          // 40
#define NBLK (GXD * GYD * NI)   // 15360
#define NPIX ((double)NI * WI * HI)
#define RSTR 68                 // LDS row stride in words; 68%32=4 -> reads hit 8/bank (uniform)
#define CSTR (RPW * RSTR)       // 544 words per channel
#define WREG (5 * CSTR)         // 2720 floats per wave

typedef float v4 __attribute__((ext_vector_type(4)));

struct W7 { float w[7]; };

// One wave, one 58x8 strip. XM: 0 = left edge tile, 1 = interior, 2 = right.
// YI: all 14 input rows in-bounds. Returns this lane's SSIM partial sum.
template <bool YI, int XM>
__device__ __forceinline__ float wave_task(
    const float* __restrict__ Xn, const float* __restrict__ Yn,
    const W7& wv, float* __restrict__ vb, int x0, int y0, int lane)
{
    const int gx   = x0 + lane - 3;
    const bool xok = (XM == 1) || (XM == 0 ? (gx >= 0) : (gx < WI));

    // ---- 28 coalesced loads (lane = consecutive col), zero-pad OOB ----
    float xr[RPW + 6], yr[RPW + 6];
#pragma unroll
    for (int j = 0; j < RPW + 6; ++j) {
        const int gy  = y0 + j - 3;
        const bool ok = xok && (YI || ((unsigned)gy < (unsigned)HI));
        float xv = 0.f, yv = 0.f;
        if (ok) { const int idx = gy * WI + gx; xv = Xn[idx]; yv = Yn[idx]; }
        xr[j] = xv; yr[j] = yv;
    }

    // ---- vertical 7-tap, 5 channels x 8 output rows, in registers ----
    float acc[5][RPW];
#pragma unroll
    for (int ch = 0; ch < 5; ++ch)
#pragma unroll
        for (int r = 0; r < RPW; ++r) acc[ch][r] = 0.f;
#pragma unroll
    for (int j = 0; j < RPW + 6; ++j) {
        const float xv = xr[j], yv = yr[j];
        const float pxx = xv * xv, pyy = yv * yv, pxy = xv * yv;
#pragma unroll
        for (int r = 0; r < RPW; ++r) {
            const int d = j - r;                 // compile-time predicate
            if (d >= 0 && d < 7) {
                const float w = wv.w[d];
                acc[0][r] += w * xv;
                acc[1][r] += w * yv;
                acc[2][r] += w * pxx;
                acc[3][r] += w * pyy;
                acc[4][r] += w * pxy;
            }
        }
    }
    // 40 b32 writes to this wave's region; bank = (lane + 4r) % 32 -> 2-way = free.
#pragma unroll
    for (int ch = 0; ch < 5; ++ch)
#pragma unroll
        for (int r = 0; r < RPW; ++r)
            vb[ch * CSTR + r * RSTR + lane] = acc[ch][r];

    __builtin_amdgcn_wave_barrier();   // scheduling fence; lgkmcnt orders the data

    // ---- horizontal 7-tap + SSIM. lane -> (row, 8 consecutive out cols) ----
    // row = lane>>3 in [0,8), xg = (lane&7)*8 in {0,8,...,56}; all lanes active.
    // b128 read banks: (4*row + xg + 4k + c) % 32 -> exactly 8 accesses/bank.
    float lsum = 0.f;
    const int row = lane >> 3;
    const int xg  = (lane & 7) << 3;
    {
        const float C1 = 0.0004f, C2 = 0.0036f, COVN = 49.f / 48.f;
        float m[RPW][5];
#pragma unroll
        for (int j = 0; j < RPW; ++j)
#pragma unroll
            for (int ch = 0; ch < 5; ++ch) m[j][ch] = 0.f;
#pragma unroll
        for (int ch = 0; ch < 5; ++ch) {
            const v4* p = (const v4*)&vb[ch * CSTR + row * RSTR + xg];
            v4 a = p[0], b = p[1], c = p[2], d4 = p[3];
            float f[16] = {a.x,a.y,a.z,a.w, b.x,b.y,b.z,b.w,
                           c.x,c.y,c.z,c.w, d4.x,d4.y,d4.z,d4.w};
#pragma unroll
            for (int j = 0; j < RPW; ++j) {
                float s = 0.f;
#pragma unroll
                for (int d = 0; d < 7; ++d) s += wv.w[d] * f[j + d];
                m[j][ch] = s;
            }
        }
#pragma unroll
        for (int j = 0; j < RPW; ++j) {
            const float mx = m[j][0], my = m[j][1];
            const float mxsq = mx * mx;
            const float mysq = my * my;
            const float mxy  = mx * my;
            const float vx   = (m[j][2] - mxsq) * COVN;
            const float vy   = (m[j][3] - mysq) * COVN;
            const float vxy  = (m[j][4] - mxy)  * COVN;
            const float num  = (2.f * mxy + C1) * (2.f * vxy + C2);
            const float den  = (mxsq + mysq + C1) * (vx + vy + C2);
            const bool valid = (xg + j < TWO) && (XM != 2 || x0 + xg + j < WI);
            lsum += valid ? num * __builtin_amdgcn_rcpf(den) : 0.f;
        }
    }
    return lsum;
}

__global__ __launch_bounds__(64) void ssim_kernel(
    const float* __restrict__ X, const float* __restrict__ Y,
    W7 wv, float* __restrict__ partial)
{
    __shared__ __align__(16) float vbuf[WREG + 16];  // +16 pad: b128 tail overrun

    const int lane = threadIdx.x;
    const int x0   = blockIdx.x * TWO;
    const int y0   = blockIdx.y * RPW;
    const float* __restrict__ Xn = X + (size_t)blockIdx.z * (WI * HI);
    const float* __restrict__ Yn = Y + (size_t)blockIdx.z * (WI * HI);

    const bool yi = (y0 >= 3) && (y0 <= HI - RPW - 3);  // all 14 input rows in-bounds
    const int  xm = (blockIdx.x == 0) ? 0 : ((blockIdx.x == GXD - 1) ? 2 : 1);

    float lsum;
    if (yi) {
        if      (xm == 0) lsum = wave_task<true, 0>(Xn, Yn, wv, vbuf, x0, y0, lane);
        else if (xm == 1) lsum = wave_task<true, 1>(Xn, Yn, wv, vbuf, x0, y0, lane);
        else              lsum = wave_task<true, 2>(Xn, Yn, wv, vbuf, x0, y0, lane);
    } else {
        if      (xm == 0) lsum = wave_task<false, 0>(Xn, Yn, wv, vbuf, x0, y0, lane);
        else if (xm == 1) lsum = wave_task<false, 1>(Xn, Yn, wv, vbuf, x0, y0, lane);
        else              lsum = wave_task<false, 2>(Xn, Yn, wv, vbuf, x0, y0, lane);
    }

    // ---- reduction: pure wave shuffle, single store. No barrier at all. ----
#pragma unroll
    for (int off = 32; off > 0; off >>= 1)
        lsum += __shfl_down(lsum, off, 64);
    if (lane == 0) {
        const int bid = (blockIdx.z * GYD + blockIdx.y) * GXD + blockIdx.x;
        partial[bid] = lsum;
    }
}

__global__ __launch_bounds__(256) void ssim_finalize(
    const float* __restrict__ partial, float* __restrict__ out)
{
    __shared__ double ws[4];
    const int tid = threadIdx.x;
    double s = 0.0;
    for (int i = tid; i < NBLK; i += 256) s += (double)partial[i];
#pragma unroll
    for (int off = 32; off > 0; off >>= 1)
        s += __shfl_down(s, off, 64);
    if ((tid & 63) == 0) ws[tid >> 6] = s;
    __syncthreads();
    if (tid == 0)
        out[0] = (float)(1.0 - ((ws[0] + ws[1]) + (ws[2] + ws[3])) / NPIX);
}

extern "C" void kernel_launch(void* const* d_in, const int* in_sizes, int n_in,
                              void* d_out, int out_size, void* d_ws, size_t ws_size,
                              hipStream_t stream) {
    const float* X = (const float*)d_in[0];
    const float* Y = (const float*)d_in[1];
    // Exact 1D Gaussian weights in fp64 (7x7 window = outer product).
    W7 wv;
    {
        double g[7], s = 0.0;
        for (int i = 0; i < 7; ++i) {
            double x = (double)(i - 3);
            g[i] = exp(-(x * x) / (2.0 * 1.5 * 1.5));
            s += g[i];
        }
        for (int i = 0; i < 7; ++i) wv.w[i] = (float)(g[i] / s);
    }

    float* partial = (float*)d_ws;   // 15360 floats, fully written every launch

    dim3 grid(GXD, GYD, NI);
    ssim_kernel<<<grid, 64, 0, stream>>>(X, Y, wv, partial);
    ssim_finalize<<<1, 256, 0, stream>>>(partial, (float*)d_out);
}

// Round 2
// 115.403 us; speedup vs baseline: 1.0179x; 1.0179x over previous
//
#include <hip/hip_runtime.h>
#include <math.h>

// SSIM on MI355X, round 8: round-6 structure (58x4 strips, 4 waves/block,
// barrier-free phases) + occupancy push:
//   - __launch_bounds__(256, 8): VGPR capped at 64 -> 8 waves/SIMD possible
//   - LDS shrunk to exactly 20480 B (no tail pad; third v4 read clamped to
//     min(xg,52), which only affects don't-care lanes) -> 8 blocks/CU exactly
//   - wsum folded into each wave's own consumed vbuf region
// Round-7 lesson: tap FMAs scale with rows/wave, so bigger strips gain no
// VALU; the kernel is latency-hiding-bound -> maximize resident waves.

#define WI 320
#define HI 320
#define NI 64
#define TWO 58                  // output cols per x-tile (64 loaded incl. halo)
#define GXD 6                   // ceil(320/58)
#define GYD 20                  // 16 output rows per block (4 waves x 4 rows)
#define NBLK (GXD * GYD * NI)   // 7680
#define NPIX ((double)NI * WI * HI)
#define WREG (5 * 4 * 64)       // per-wave LDS floats: 5 ch x 4 rows x 64 cols

typedef float v4 __attribute__((ext_vector_type(4)));

struct W7 { float w[7]; };

// One wave, one 58x4 strip. XM: 0 = left edge tile, 1 = interior, 2 = right.
// YI: all 10 input rows in-bounds. Returns this lane's SSIM partial sum.
template <bool YI, int XM>
__device__ __forceinline__ float wave_task(
    const float* __restrict__ Xn, const float* __restrict__ Yn,
    const W7& wv, float* __restrict__ vb, int x0, int y0, int lane)
{
    const int gx   = x0 + lane - 3;
    const bool xok = (XM == 1) || (XM == 0 ? (gx >= 0) : (gx < WI));

    // ---- 20 coalesced loads (lane = consecutive col), zero-pad OOB ----
    float xr[10], yr[10];
#pragma unroll
    for (int j = 0; j < 10; ++j) {
        const int gy  = y0 + j - 3;
        const bool ok = xok && (YI || ((unsigned)gy < (unsigned)HI));
        float xv = 0.f, yv = 0.f;
        if (ok) { const int idx = gy * WI + gx; xv = Xn[idx]; yv = Yn[idx]; }
        xr[j] = xv; yr[j] = yv;
    }

    // ---- vertical 7-tap, 5 channels x 4 output rows, in registers ----
    float acc[5][4];
#pragma unroll
    for (int ch = 0; ch < 5; ++ch)
#pragma unroll
        for (int r = 0; r < 4; ++r) acc[ch][r] = 0.f;
#pragma unroll
    for (int j = 0; j < 10; ++j) {
        const float xv = xr[j], yv = yr[j];
        const float pxx = xv * xv, pyy = yv * yv, pxy = xv * yv;
#pragma unroll
        for (int r = 0; r < 4; ++r) {
            const int d = j - r;                 // compile-time predicate
            if (d >= 0 && d < 7) {
                const float w = wv.w[d];
                acc[0][r] += w * xv;
                acc[1][r] += w * yv;
                acc[2][r] += w * pxx;
                acc[3][r] += w * pyy;
                acc[4][r] += w * pxy;
            }
        }
    }
    // 20 b32 writes to this wave's private region; col = lane (2-way = free).
#pragma unroll
    for (int ch = 0; ch < 5; ++ch)
#pragma unroll
        for (int r = 0; r < 4; ++r)
            vb[ch * 256 + r * 64 + lane] = acc[ch][r];

    __builtin_amdgcn_wave_barrier();   // scheduling fence; lgkmcnt orders the data

    // ---- horizontal 7-tap + SSIM. lane -> (row, 4 consecutive out cols) ----
    float lsum = 0.f;
    const int row = lane >> 4;
    const int xg  = (lane & 15) << 2;          // 0,4,...,60
    if (xg < TWO) {                            // xg==60 lanes idle
        // Third v4 (f[8..11]) is only NEEDED for xg<=52 (at xg=56 the valid
        // outputs j<2 use f[0..7] only). Clamp its address so every LDS
        // access stays inside this wave's 1280-float region -> no pad needed.
        const int xg3 = (xg > 52) ? 52 : xg;
        const float C1 = 0.0004f, C2 = 0.0036f, COVN = 49.f / 48.f;
        float m[4][5];
#pragma unroll
        for (int j = 0; j < 4; ++j)
#pragma unroll
            for (int ch = 0; ch < 5; ++ch) m[j][ch] = 0.f;
#pragma unroll
        for (int ch = 0; ch < 5; ++ch) {
            const float* base = &vb[ch * 256 + row * 64];
            v4 a = *(const v4*)&base[xg];
            v4 b = *(const v4*)&base[xg + 4];
            v4 c = *(const v4*)&base[xg3 + 8];
            float f[12] = {a.x,a.y,a.z,a.w, b.x,b.y,b.z,b.w, c.x,c.y,c.z,c.w};
#pragma unroll
            for (int j = 0; j < 4; ++j) {
                float s = 0.f;
#pragma unroll
                for (int d = 0; d < 7; ++d) s += wv.w[d] * f[j + d];
                m[j][ch] = s;
            }
        }
#pragma unroll
        for (int j = 0; j < 4; ++j) {
            const float mx = m[j][0], my = m[j][1];
            const float mxsq = mx * mx;
            const float mysq = my * my;
            const float mxy  = mx * my;
            const float vx   = (m[j][2] - mxsq) * COVN;
            const float vy   = (m[j][3] - mysq) * COVN;
            const float vxy  = (m[j][4] - mxy)  * COVN;
            const float num  = (2.f * mxy + C1) * (2.f * vxy + C2);
            const float den  = (mxsq + mysq + C1) * (vx + vy + C2);
            const bool valid = (xg + j < TWO) && (XM != 2 || x0 + xg + j < WI);
            lsum += valid ? num * __builtin_amdgcn_rcpf(den) : 0.f;
        }
    }
    return lsum;
}

__global__ __launch_bounds__(256, 8) void ssim_kernel(
    const float* __restrict__ X, const float* __restrict__ Y,
    W7 wv, float* __restrict__ partial)
{
    __shared__ __align__(16) float vbuf[4 * WREG];   // exactly 20480 B -> 8 blocks/CU

    const int tid  = threadIdx.x;
    const int lane = tid & 63;
    const int w    = tid >> 6;
    const int x0   = blockIdx.x * TWO;
    const int y0   = blockIdx.y * 16 + w * 4;  // first output row of this wave
    const float* __restrict__ Xn = X + (size_t)blockIdx.z * (WI * HI);
    const float* __restrict__ Yn = Y + (size_t)blockIdx.z * (WI * HI);
    float* vb = vbuf + w * WREG;

    const bool yi = (y0 >= 3) && (y0 <= HI - 7);  // all 10 input rows in-bounds
    const int  xm = (blockIdx.x == 0) ? 0 : ((blockIdx.x == GXD - 1) ? 2 : 1);

    float lsum;
    if (yi) {
        if      (xm == 0) lsum = wave_task<true, 0>(Xn, Yn, wv, vb, x0, y0, lane);
        else if (xm == 1) lsum = wave_task<true, 1>(Xn, Yn, wv, vb, x0, y0, lane);
        else              lsum = wave_task<true, 2>(Xn, Yn, wv, vb, x0, y0, lane);
    } else {
        if      (xm == 0) lsum = wave_task<false, 0>(Xn, Yn, wv, vb, x0, y0, lane);
        else if (xm == 1) lsum = wave_task<false, 1>(Xn, Yn, wv, vb, x0, y0, lane);
        else              lsum = wave_task<false, 2>(Xn, Yn, wv, vb, x0, y0, lane);
    }

    // ---- reduction: wave shuffle -> own (consumed) vbuf slot -> one barrier ----
#pragma unroll
    for (int off = 32; off > 0; off >>= 1)
        lsum += __shfl_down(lsum, off, 64);
    if (lane == 0) vbuf[w * WREG] = lsum;   // wave w writes only its own region
    __syncthreads();
    if (tid == 0) {
        const int bid = (blockIdx.z * GYD + blockIdx.y) * GXD + blockIdx.x;
        partial[bid] = (vbuf[0] + vbuf[WREG]) + (vbuf[2 * WREG] + vbuf[3 * WREG]);
    }
}

__global__ __launch_bounds__(256) void ssim_finalize(
    const float* __restrict__ partial, float* __restrict__ out)
{
    __shared__ double ws[4];
    const int tid = threadIdx.x;
    double s = 0.0;
    for (int i = tid; i < NBLK; i += 256) s += (double)partial[i];
#pragma unroll
    for (int off = 32; off > 0; off >>= 1)
        s += __shfl_down(s, off, 64);
    if ((tid & 63) == 0) ws[tid >> 6] = s;
    __syncthreads();
    if (tid == 0)
        out[0] = (float)(1.0 - ((ws[0] + ws[1]) + (ws[2] + ws[3])) / NPIX);
}

extern "C" void kernel_launch(void* const* d_in, const int* in_sizes, int n_in,
                              void* d_out, int out_size, void* d_ws, size_t ws_size,
                              hipStream_t stream) {
    const float* X = (const float*)d_in[0];
    const float* Y = (const float*)d_in[1];
    // Exact 1D Gaussian weights in fp64 (7x7 window = outer product).
    W7 wv;
    {
        double g[7], s = 0.0;
        for (int i = 0; i < 7; ++i) {
            double x = (double)(i - 3);
            g[i] = exp(-(x * x) / (2.0 * 1.5 * 1.5));
            s += g[i];
        }
        for (int i = 0; i < 7; ++i) wv.w[i] = (float)(g[i] / s);
    }

    float* partial = (float*)d_ws;   // 7680 floats, fully written every launch

    dim3 grid(GXD, GYD, NI);
    ssim_kernel<<<grid, 256, 0, stream>>>(X, Y, wv, partial);
    ssim_finalize<<<1, 256, 0, stream>>>(partial, (float*)d_out);
}

// Round 3
// 110.891 us; speedup vs baseline: 1.0593x; 1.0407x over previous
//
#include <hip/hip_runtime.h>
#include <math.h>

// SSIM on MI355X, round 9: round-6 dataflow (58x4 strips, 4 waves/block,
// barrier-free phases) + FEASIBLE occupancy push.
// Round-8 lesson: __launch_bounds__(256,8) clamped VGPR to 32 -> ~11 MB of
// scratch spills (WRITE_SIZE 11331 KB vs 30 KB legit). The kernel needs ~50
// live VGPRs (20 load dests + 20 accumulators + addressing).
// This round: __launch_bounds__(256,7) -> VGPR cap 72 (no spill expected),
// 7 blocks/CU = 28 waves/CU; LDS 7 x 20480 B = 143 KB <= 160 KB (not binding).

#define WI 320
#define HI 320
#define NI 64
#define TWO 58                  // output cols per x-tile (64 loaded incl. halo)
#define GXD 6                   // ceil(320/58)
#define GYD 20                  // 16 output rows per block (4 waves x 4 rows)
#define NBLK (GXD * GYD * NI)   // 7680
#define NPIX ((double)NI * WI * HI)
#define WREG (5 * 4 * 64)       // per-wave LDS floats: 5 ch x 4 rows x 64 cols

typedef float v4 __attribute__((ext_vector_type(4)));

struct W7 { float w[7]; };

// One wave, one 58x4 strip. XM: 0 = left edge tile, 1 = interior, 2 = right.
// YI: all 10 input rows in-bounds. Returns this lane's SSIM partial sum.
template <bool YI, int XM>
__device__ __forceinline__ float wave_task(
    const float* __restrict__ Xn, const float* __restrict__ Yn,
    const W7& wv, float* __restrict__ vb, int x0, int y0, int lane)
{
    const int gx   = x0 + lane - 3;
    const bool xok = (XM == 1) || (XM == 0 ? (gx >= 0) : (gx < WI));

    // ---- 20 coalesced loads (lane = consecutive col), zero-pad OOB ----
    float xr[10], yr[10];
#pragma unroll
    for (int j = 0; j < 10; ++j) {
        const int gy  = y0 + j - 3;
        const bool ok = xok && (YI || ((unsigned)gy < (unsigned)HI));
        float xv = 0.f, yv = 0.f;
        if (ok) { const int idx = gy * WI + gx; xv = Xn[idx]; yv = Yn[idx]; }
        xr[j] = xv; yr[j] = yv;
    }

    // ---- vertical 7-tap, 5 channels x 4 output rows, in registers ----
    float acc[5][4];
#pragma unroll
    for (int ch = 0; ch < 5; ++ch)
#pragma unroll
        for (int r = 0; r < 4; ++r) acc[ch][r] = 0.f;
#pragma unroll
    for (int j = 0; j < 10; ++j) {
        const float xv = xr[j], yv = yr[j];
        const float pxx = xv * xv, pyy = yv * yv, pxy = xv * yv;
#pragma unroll
        for (int r = 0; r < 4; ++r) {
            const int d = j - r;                 // compile-time predicate
            if (d >= 0 && d < 7) {
                const float w = wv.w[d];
                acc[0][r] += w * xv;
                acc[1][r] += w * yv;
                acc[2][r] += w * pxx;
                acc[3][r] += w * pyy;
                acc[4][r] += w * pxy;
            }
        }
    }
    // 20 b32 writes to this wave's private region; col = lane (2-way = free).
#pragma unroll
    for (int ch = 0; ch < 5; ++ch)
#pragma unroll
        for (int r = 0; r < 4; ++r)
            vb[ch * 256 + r * 64 + lane] = acc[ch][r];

    __builtin_amdgcn_wave_barrier();   // scheduling fence; lgkmcnt orders the data

    // ---- horizontal 7-tap + SSIM. lane -> (row, 4 consecutive out cols) ----
    float lsum = 0.f;
    const int row = lane >> 4;
    const int xg  = (lane & 15) << 2;          // 0,4,...,60
    if (xg < TWO) {                            // xg==60 lanes idle
        // Third v4 (f[8..11]) is only NEEDED for xg<=52 (at xg=56 the valid
        // outputs j<2 use f[0..7] only). Clamp its address so every LDS
        // access stays inside this wave's 1280-float region -> no pad needed.
        const int xg3 = (xg > 52) ? 52 : xg;
        const float C1 = 0.0004f, C2 = 0.0036f, COVN = 49.f / 48.f;
        float m[4][5];
#pragma unroll
        for (int j = 0; j < 4; ++j)
#pragma unroll
            for (int ch = 0; ch < 5; ++ch) m[j][ch] = 0.f;
#pragma unroll
        for (int ch = 0; ch < 5; ++ch) {
            const float* base = &vb[ch * 256 + row * 64];
            v4 a = *(const v4*)&base[xg];
            v4 b = *(const v4*)&base[xg + 4];
            v4 c = *(const v4*)&base[xg3 + 8];
            float f[12] = {a.x,a.y,a.z,a.w, b.x,b.y,b.z,b.w, c.x,c.y,c.z,c.w};
#pragma unroll
            for (int j = 0; j < 4; ++j) {
                float s = 0.f;
#pragma unroll
                for (int d = 0; d < 7; ++d) s += wv.w[d] * f[j + d];
                m[j][ch] = s;
            }
        }
#pragma unroll
        for (int j = 0; j < 4; ++j) {
            const float mx = m[j][0], my = m[j][1];
            const float mxsq = mx * mx;
            const float mysq = my * my;
            const float mxy  = mx * my;
            const float vx   = (m[j][2] - mxsq) * COVN;
            const float vy   = (m[j][3] - mysq) * COVN;
            const float vxy  = (m[j][4] - mxy)  * COVN;
            const float num  = (2.f * mxy + C1) * (2.f * vxy + C2);
            const float den  = (mxsq + mysq + C1) * (vx + vy + C2);
            const bool valid = (xg + j < TWO) && (XM != 2 || x0 + xg + j < WI);
            lsum += valid ? num * __builtin_amdgcn_rcpf(den) : 0.f;
        }
    }
    return lsum;
}

__global__ __launch_bounds__(256, 7) void ssim_kernel(
    const float* __restrict__ X, const float* __restrict__ Y,
    W7 wv, float* __restrict__ partial)
{
    __shared__ __align__(16) float vbuf[4 * WREG];   // exactly 20480 B

    const int tid  = threadIdx.x;
    const int lane = tid & 63;
    const int w    = tid >> 6;
    const int x0   = blockIdx.x * TWO;
    const int y0   = blockIdx.y * 16 + w * 4;  // first output row of this wave
    const float* __restrict__ Xn = X + (size_t)blockIdx.z * (WI * HI);
    const float* __restrict__ Yn = Y + (size_t)blockIdx.z * (WI * HI);
    float* vb = vbuf + w * WREG;

    const bool yi = (y0 >= 3) && (y0 <= HI - 7);  // all 10 input rows in-bounds
    const int  xm = (blockIdx.x == 0) ? 0 : ((blockIdx.x == GXD - 1) ? 2 : 1);

    float lsum;
    if (yi) {
        if      (xm == 0) lsum = wave_task<true, 0>(Xn, Yn, wv, vb, x0, y0, lane);
        else if (xm == 1) lsum = wave_task<true, 1>(Xn, Yn, wv, vb, x0, y0, lane);
        else              lsum = wave_task<true, 2>(Xn, Yn, wv, vb, x0, y0, lane);
    } else {
        if      (xm == 0) lsum = wave_task<false, 0>(Xn, Yn, wv, vb, x0, y0, lane);
        else if (xm == 1) lsum = wave_task<false, 1>(Xn, Yn, wv, vb, x0, y0, lane);
        else              lsum = wave_task<false, 2>(Xn, Yn, wv, vb, x0, y0, lane);
    }

    // ---- reduction: wave shuffle -> own (consumed) vbuf slot -> one barrier ----
#pragma unroll
    for (int off = 32; off > 0; off >>= 1)
        lsum += __shfl_down(lsum, off, 64);
    if (lane == 0) vbuf[w * WREG] = lsum;   // wave w writes only its own region
    __syncthreads();
    if (tid == 0) {
        const int bid = (blockIdx.z * GYD + blockIdx.y) * GXD + blockIdx.x;
        partial[bid] = (vbuf[0] + vbuf[WREG]) + (vbuf[2 * WREG] + vbuf[3 * WREG]);
    }
}

__global__ __launch_bounds__(256) void ssim_finalize(
    const float* __restrict__ partial, float* __restrict__ out)
{
    __shared__ double ws[4];
    const int tid = threadIdx.x;
    double s = 0.0;
    for (int i = tid; i < NBLK; i += 256) s += (double)partial[i];
#pragma unroll
    for (int off = 32; off > 0; off >>= 1)
        s += __shfl_down(s, off, 64);
    if ((tid & 63) == 0) ws[tid >> 6] = s;
    __syncthreads();
    if (tid == 0)
        out[0] = (float)(1.0 - ((ws[0] + ws[1]) + (ws[2] + ws[3])) / NPIX);
}

extern "C" void kernel_launch(void* const* d_in, const int* in_sizes, int n_in,
                              void* d_out, int out_size, void* d_ws, size_t ws_size,
                              hipStream_t stream) {
    const float* X = (const float*)d_in[0];
    const float* Y = (const float*)d_in[1];
    // Exact 1D Gaussian weights in fp64 (7x7 window = outer product).
    W7 wv;
    {
        double g[7], s = 0.0;
        for (int i = 0; i < 7; ++i) {
            double x = (double)(i - 3);
            g[i] = exp(-(x * x) / (2.0 * 1.5 * 1.5));
            s += g[i];
        }
        for (int i = 0; i < 7; ++i) wv.w[i] = (float)(g[i] / s);
    }

    float* partial = (float*)d_ws;   // 7680 floats, fully written every launch

    dim3 grid(GXD, GYD, NI);
    ssim_kernel<<<grid, 256, 0, stream>>>(X, Y, wv, partial);
    ssim_finalize<<<1, 256, 0, stream>>>(partial, (float*)d_out);
}

// Round 4
// 106.713 us; speedup vs baseline: 1.1007x; 1.0392x over previous
//
#include <hip/hip_runtime.h>
#include <math.h>

// SSIM on MI355X, round 10: image-PAIR packing with float2 -> v_pk_fma_f32.
// Every op in this kernel is element-wise across images, so each wave now
// processes the same 58x4 strip of TWO images (blockIdx.z = pair index),
// with all tap/SSIM math in <2 x float> (gfx950 packed fp32: one
// v_pk_fma_f32 does both images). Per-strip VALU instr count ~halves;
// per-image arithmetic order is bit-identical (independent vector lanes).
// Costs: LDS 40960 B/block -> exactly 4 blocks/CU (16 waves/CU), VGPR ~100
// (cap 128 via launch_bounds(256,4)).
// Round-9 lesson: occupancy axis exhausted (28 waves/CU == round-6 time);
// kernel is VALU-issue-bound (~450 instr/wave ~= 11 us chip-wide).

#define WI 320
#define HI 320
#define NI 64
#define NZ (NI / 2)             // 32 image pairs
#define TWO 58                  // output cols per x-tile (64 loaded incl. halo)
#define GXD 6                   // ceil(320/58)
#define GYD 20                  // 16 output rows per block (4 waves x 4 rows)
#define NBLK (GXD * GYD * NZ)   // 3840 blocks
#define NPART (2 * NBLK)        // 7680 partial floats (2 images per block)
#define NPIX ((double)NI * WI * HI)
#define IMG (WI * HI)
#define WREG (5 * 4 * 64)       // per-wave LDS float2 count: 1280 (10240 B)

typedef float v2f __attribute__((ext_vector_type(2)));
typedef float v4f __attribute__((ext_vector_type(4)));

struct W7 { float w[7]; };

// One wave, one 58x4 strip of an image PAIR. XM: 0=left tile, 1=interior,
// 2=right. YI: all 10 input rows in-bounds. Returns packed SSIM partials.
template <bool YI, int XM>
__device__ __forceinline__ v2f wave_task(
    const float* __restrict__ X0, const float* __restrict__ X1,
    const float* __restrict__ Y0, const float* __restrict__ Y1,
    const W7& wv, v2f* __restrict__ vb, int x0, int y0, int lane)
{
    const int gx   = x0 + lane - 3;
    const bool xok = (XM == 1) || (XM == 0 ? (gx >= 0) : (gx < WI));

    // ---- 40 coalesced dword loads (lane = consecutive col), zero-pad OOB ----
    v2f xr[10], yr[10];
#pragma unroll
    for (int j = 0; j < 10; ++j) {
        const int gy  = y0 + j - 3;
        const bool ok = xok && (YI || ((unsigned)gy < (unsigned)HI));
        v2f xv = {0.f, 0.f}, yv = {0.f, 0.f};
        if (ok) {
            const int idx = gy * WI + gx;
            xv.x = X0[idx]; xv.y = X1[idx];
            yv.x = Y0[idx]; yv.y = Y1[idx];
        }
        xr[j] = xv; yr[j] = yv;
    }

    // ---- vertical 7-tap, 5 channels x 4 rows, packed over the image pair ----
    v2f acc[5][4];
#pragma unroll
    for (int ch = 0; ch < 5; ++ch)
#pragma unroll
        for (int r = 0; r < 4; ++r) acc[ch][r] = (v2f){0.f, 0.f};
#pragma unroll
    for (int j = 0; j < 10; ++j) {
        const v2f xv = xr[j], yv = yr[j];
        const v2f pxx = xv * xv, pyy = yv * yv, pxy = xv * yv;
#pragma unroll
        for (int r = 0; r < 4; ++r) {
            const int d = j - r;                 // compile-time predicate
            if (d >= 0 && d < 7) {
                const v2f w2 = {wv.w[d], wv.w[d]};
                acc[0][r] = __builtin_elementwise_fma(w2, xv,  acc[0][r]);
                acc[1][r] = __builtin_elementwise_fma(w2, yv,  acc[1][r]);
                acc[2][r] = __builtin_elementwise_fma(w2, pxx, acc[2][r]);
                acc[3][r] = __builtin_elementwise_fma(w2, pyy, acc[3][r]);
                acc[4][r] = __builtin_elementwise_fma(w2, pxy, acc[4][r]);
            }
        }
    }
    // 20 b64 writes to this wave's private region; uniform 4 words/bank = free.
#pragma unroll
    for (int ch = 0; ch < 5; ++ch)
#pragma unroll
        for (int r = 0; r < 4; ++r)
            vb[ch * 256 + r * 64 + lane] = acc[ch][r];

    __builtin_amdgcn_wave_barrier();   // scheduling fence; lgkmcnt orders the data

    // ---- horizontal 7-tap + SSIM. lane -> (row, 4 consecutive out cols) ----
    v2f lsum = {0.f, 0.f};
    const int row = lane >> 4;
    const int xg  = (lane & 15) << 2;          // 0,4,...,60
    if (xg < TWO) {                            // xg==60 lanes idle
        // f2[8..11] only NEEDED for xg<=52 (at xg=56 valid outputs j<2 use
        // f2[0..7]). Clamp those addresses -> all reads in-bounds, no pad.
        const int xg3 = (xg > 52) ? 52 : xg;
        const v2f zero = {0.f, 0.f};
        v2f m[4][5];
#pragma unroll
        for (int ch = 0; ch < 5; ++ch) {
            const v2f* base = &vb[ch * 256 + row * 64];
            const v4f q0 = *(const v4f*)&base[xg];
            const v4f q1 = *(const v4f*)&base[xg + 2];
            const v4f q2 = *(const v4f*)&base[xg + 4];
            const v4f q3 = *(const v4f*)&base[xg + 6];
            const v4f q4 = *(const v4f*)&base[xg3 + 8];
            const v4f q5 = *(const v4f*)&base[xg3 + 10];
            const v2f f2[12] = {
                {q0.x,q0.y},{q0.z,q0.w},{q1.x,q1.y},{q1.z,q1.w},
                {q2.x,q2.y},{q2.z,q2.w},{q3.x,q3.y},{q3.z,q3.w},
                {q4.x,q4.y},{q4.z,q4.w},{q5.x,q5.y},{q5.z,q5.w}};
#pragma unroll
            for (int j = 0; j < 4; ++j) {
                v2f s = zero;
#pragma unroll
                for (int d = 0; d < 7; ++d) {
                    const v2f w2 = {wv.w[d], wv.w[d]};
                    s = __builtin_elementwise_fma(w2, f2[j + d], s);
                }
                m[j][ch] = s;
            }
        }
#pragma unroll
        for (int j = 0; j < 4; ++j) {
            const v2f mx = m[j][0], my = m[j][1];
            const v2f mxsq = mx * mx;
            const v2f mysq = my * my;
            const v2f mxy  = mx * my;
            const v2f vx   = (m[j][2] - mxsq) * 1.0208333333333333f;
            const v2f vy   = (m[j][3] - mysq) * 1.0208333333333333f;
            const v2f vxy  = (m[j][4] - mxy)  * 1.0208333333333333f;
            const v2f num  = (2.f * mxy + 0.0004f) * (2.f * vxy + 0.0036f);
            const v2f den  = (mxsq + mysq + 0.0004f) * (vx + vy + 0.0036f);
            v2f rden;
            rden.x = __builtin_amdgcn_rcpf(den.x);
            rden.y = __builtin_amdgcn_rcpf(den.y);
            const v2f term = num * rden;
            const bool valid = (xg + j < TWO) && (XM != 2 || x0 + xg + j < WI);
            lsum += valid ? term : zero;
        }
    }
    return lsum;
}

__global__ __launch_bounds__(256, 4) void ssim_kernel(
    const float* __restrict__ X, const float* __restrict__ Y,
    W7 wv, float* __restrict__ partial)
{
    __shared__ __align__(16) v2f vbuf[4 * WREG];   // exactly 40960 B -> 4 blocks/CU

    const int tid  = threadIdx.x;
    const int lane = tid & 63;
    const int w    = tid >> 6;
    const int x0   = blockIdx.x * TWO;
    const int y0   = blockIdx.y * 16 + w * 4;  // first output row of this wave
    const float* __restrict__ X0 = X + (size_t)(2 * blockIdx.z) * IMG;
    const float* __restrict__ X1 = X0 + IMG;
    const float* __restrict__ Y0 = Y + (size_t)(2 * blockIdx.z) * IMG;
    const float* __restrict__ Y1 = Y0 + IMG;
    v2f* vb = vbuf + w * WREG;

    const bool yi = (y0 >= 3) && (y0 <= HI - 7);  // all 10 input rows in-bounds
    const int  xm = (blockIdx.x == 0) ? 0 : ((blockIdx.x == GXD - 1) ? 2 : 1);

    v2f lsum;
    if (yi) {
        if      (xm == 0) lsum = wave_task<true, 0>(X0, X1, Y0, Y1, wv, vb, x0, y0, lane);
        else if (xm == 1) lsum = wave_task<true, 1>(X0, X1, Y0, Y1, wv, vb, x0, y0, lane);
        else              lsum = wave_task<true, 2>(X0, X1, Y0, Y1, wv, vb, x0, y0, lane);
    } else {
        if      (xm == 0) lsum = wave_task<false, 0>(X0, X1, Y0, Y1, wv, vb, x0, y0, lane);
        else if (xm == 1) lsum = wave_task<false, 1>(X0, X1, Y0, Y1, wv, vb, x0, y0, lane);
        else              lsum = wave_task<false, 2>(X0, X1, Y0, Y1, wv, vb, x0, y0, lane);
    }

    // ---- reduction: wave shuffle -> own (consumed) vbuf slot -> one barrier ----
#pragma unroll
    for (int off = 32; off > 0; off >>= 1) {
        lsum.x += __shfl_down(lsum.x, off, 64);
        lsum.y += __shfl_down(lsum.y, off, 64);
    }
    if (lane == 0) vb[0] = lsum;   // wave w writes only its own (consumed) region
    __syncthreads();
    if (tid == 0) {
        const int bid = (blockIdx.z * GYD + blockIdx.y) * GXD + blockIdx.x;
        const v2f t = (vbuf[0] + vbuf[WREG]) + (vbuf[2 * WREG] + vbuf[3 * WREG]);
        partial[2 * bid]     = t.x;
        partial[2 * bid + 1] = t.y;
    }
}

__global__ __launch_bounds__(256) void ssim_finalize(
    const float* __restrict__ partial, float* __restrict__ out)
{
    __shared__ double ws[4];
    const int tid = threadIdx.x;
    double s = 0.0;
    for (int i = tid; i < NPART; i += 256) s += (double)partial[i];
#pragma unroll
    for (int off = 32; off > 0; off >>= 1)
        s += __shfl_down(s, off, 64);
    if ((tid & 63) == 0) ws[tid >> 6] = s;
    __syncthreads();
    if (tid == 0)
        out[0] = (float)(1.0 - ((ws[0] + ws[1]) + (ws[2] + ws[3])) / NPIX);
}

extern "C" void kernel_launch(void* const* d_in, const int* in_sizes, int n_in,
                              void* d_out, int out_size, void* d_ws, size_t ws_size,
                              hipStream_t stream) {
    const float* X = (const float*)d_in[0];
    const float* Y = (const float*)d_in[1];
    // Exact 1D Gaussian weights in fp64 (7x7 window = outer product).
    W7 wv;
    {
        double g[7], s = 0.0;
        for (int i = 0; i < 7; ++i) {
            double x = (double)(i - 3);
            g[i] = exp(-(x * x) / (2.0 * 1.5 * 1.5));
            s += g[i];
        }
        for (int i = 0; i < 7; ++i) wv.w[i] = (float)(g[i] / s);
    }

    float* partial = (float*)d_ws;   // 7680 floats, fully written every launch

    dim3 grid(GXD, GYD, NZ);
    ssim_kernel<<<grid, 256, 0, stream>>>(X, Y, wv, partial);
    ssim_finalize<<<1, 256, 0, stream>>>(partial, (float*)d_out);
}